// Round 9
// baseline (883.264 us; speedup 1.0000x reference)
//
#include <hip/hip_runtime.h>
#include <cstdint>
#include <cstddef>

#define B_   4096   // batch
#define ISZ  1024   // input size
#define SW   4096   // state width (input state last dim)
#define OHW  2048   // output hidden width (4 depths x 512)
#define HU_  512    // hidden units per (depth,stack)
#define NG   2048   // 4*HU gate rows per (depth,stack)

// packed-A geometry: 16x32 subtiles, [row16][kblk][lane][8], lane=((k>>3)&3)*16+(m&15)
#define PK_SUB   512                  // shorts per subtile
#define PK_NKB1  32                   // ISZ/32
#define PK_NKB2  16                   // HU_/32
#define PK_DSTR  (256 * 32 * 512)     // per-depth stride of packed (B x ISZ) = 4.19M shorts

typedef float f32x4 __attribute__((ext_vector_type(4)));
typedef short bf16x8 __attribute__((ext_vector_type(8)));

__device__ __forceinline__ short f2bf(float x) {
    union { float f; unsigned u; } v; v.f = x;
    unsigned r = v.u + 0x7fffu + ((v.u >> 16) & 1u);   // RNE
    return (short)(r >> 16);
}
__device__ __forceinline__ float sigm(float x)   { return 1.f / (1.f + __expf(-x)); }
__device__ __forceinline__ float tanh_f(float x) { return 2.f / (1.f + __expf(-2.f * x)) - 1.f; }

// async global->LDS, 16B per lane; LDS dest is wave-uniform base + lane*16.
__device__ __forceinline__ void async16(const void* g, void* l) {
    __builtin_amdgcn_global_load_lds((__attribute__((address_space(1))) void*)g,
                                     (__attribute__((address_space(3))) void*)l,
                                     16, 0, 0);
}

#define VM_BAR(N) asm volatile("s_waitcnt vmcnt(" #N ")\n\ts_barrier" ::: "memory")

// ---------------------------------------------------------------- flat f32 -> bf16
__global__ __launch_bounds__(256) void cvt_kernel(const float* __restrict__ src,
                                                  short* __restrict__ dst, long n) {
    long i = ((long)blockIdx.x * 256 + threadIdx.x) * 8;
    if (i >= n) return;
    float4 a = *(const float4*)(src + i);
    float4 b = *(const float4*)(src + i + 4);
    bf16x8 o;
    o[0] = f2bf(a.x); o[1] = f2bf(a.y); o[2] = f2bf(a.z); o[3] = f2bf(a.w);
    o[4] = f2bf(b.x); o[5] = f2bf(b.y); o[6] = f2bf(b.z); o[7] = f2bf(b.w);
    *(bf16x8*)(dst + i) = o;
}

// ---- input (B x ISZ) f32 -> packed-A bf16 (nkb=32)
__global__ __launch_bounds__(256) void cvt_pack_kernel(const float* __restrict__ src,
                                                       short* __restrict__ dst) {
    long i = ((long)blockIdx.x * 256 + threadIdx.x) * 8;   // over B_*ISZ
    const int m = (int)(i >> 10), c = (int)(i & 1023);
    float4 a = *(const float4*)(src + i);
    float4 b = *(const float4*)(src + i + 4);
    bf16x8 o;
    o[0] = f2bf(a.x); o[1] = f2bf(a.y); o[2] = f2bf(a.z); o[3] = f2bf(a.w);
    o[4] = f2bf(b.x); o[5] = f2bf(b.y); o[6] = f2bf(b.z); o[7] = f2bf(b.w);
    size_t off = ((size_t)(m >> 4) * PK_NKB1 + (c >> 5)) * PK_SUB
               + ((((c >> 3) & 3) * 16) + (m & 15)) * 8;
    *(bf16x8*)(dst + off) = o;
}

// ---- state[0,:,:,0:2048] f32 -> packed-A bf16 per (j,d) block (nkb=16)
__global__ __launch_bounds__(256) void cvt_h_pack_kernel(const float* __restrict__ src,
                                                         short* __restrict__ dst) {
    long i = ((long)blockIdx.x * 256 + threadIdx.x) * 8;   // over 2*B*OHW
    const long row = i >> 11;            // j*B + m
    const int  c   = (int)(i & 2047);
    const int  j   = (int)(row >> 12);
    const int  m   = (int)(row & 4095);
    const int  d   = c >> 9;
    const int  k   = c & 511;
    const float* s = src + row * SW + c;
    float4 a = *(const float4*)(s);
    float4 b = *(const float4*)(s + 4);
    bf16x8 o;
    o[0] = f2bf(a.x); o[1] = f2bf(a.y); o[2] = f2bf(a.z); o[3] = f2bf(a.w);
    o[4] = f2bf(b.x); o[5] = f2bf(b.y); o[6] = f2bf(b.z); o[7] = f2bf(b.w);
    size_t off = ((size_t)(j * 4 + d) * 4096 + (size_t)(m >> 4) * PK_NKB2 + (k >> 5)) * PK_SUB
               + ((((k >> 3) & 3) * 16) + (m & 15)) * 8;
    *(bf16x8*)(dst + off) = o;
}

// 16-MFMA cluster, setprio-wrapped (T5); AA selects lo/hi A half.
#define MMA_BLK(BB, AA, AR0, N0)                                                  \
  do {                                                                            \
    __builtin_amdgcn_s_setprio(1);                                                \
    _Pragma("unroll")                                                             \
    for (int mtl = 0; mtl < 4; ++mtl) {                                           \
      _Pragma("unroll")                                                           \
      for (int nn = 0; nn < 2; ++nn) {                                            \
        _Pragma("unroll")                                                         \
        for (int ks = 0; ks < 2; ++ks) {                                          \
          acc[(AR0) + mtl][(N0) + nn] = __builtin_amdgcn_mfma_f32_16x16x32_bf16(  \
              AA[mtl][ks], BB[nn][ks], acc[(AR0) + mtl][(N0) + nn], 0, 0, 0);     \
        }                                                                         \
      }                                                                           \
    }                                                                             \
    __builtin_amdgcn_s_setprio(0);                                                \
  } while (0)

// B-tile row rb (0..255) -> global gate row: gate=(rb>>4)&3, hid=h0+((rb>>6)<<4)+(rb&15)
#define GROW(rb) (((((rb) >> 4) & 3) << 9) + h0 + ((((rb) >> 6)) << 4) + ((rb) & 15))

// ---------------------------------------------------------------- gates3: fused gates GEMM + LSTM cell
// 256x256 tile, 8 waves (2Mx4N), BK=64. A operand DIRECT from global in packed
// fragment-tiled layout (one coalesced 1KB wave-load per fragment; compiler-tracked
// waits). Only B staged in LDS (2 x 32KB dbuf, XOR-swizzled). Per tile:
//   ldA(t) x16 | fence | stage B(t+1) x4 | rdB + 64 MFMA | VM_BAR(0)
// Issue order A-before-B means compiler waits on A never drain B; VM_BAR(0) waits
// only on B staged ~full tile earlier (L2-hot weights -> ~free).
__global__ __launch_bounds__(512) void gates3_kernel(
    const short* __restrict__ Apk, long a_dstride,       // packed K1 A (nkb=32); depth stride
    const short* __restrict__ Hpk,                       // packed K2 A (nkb=16), (j*4+d) blocks
    const short* __restrict__ Wihb, const short* __restrict__ Whhb,
    const float* __restrict__ b_ih, const float* __restrict__ b_hh,
    const float* __restrict__ state,                     // f32 original (2,2,B,SW)
    float* __restrict__ out_ho, float* __restrict__ out_state,
    short* __restrict__ h0b,                             // bf16 h_out (stack0 only)
    int j)
{
    extern __shared__ short lds[];   // 2 bufs x (B 256x64) bf16 = 65536 B

    const int tid  = threadIdx.x;
    const int wave = tid >> 6;
    const int lane = tid & 63;
    const int wm   = wave >> 2;      // 0..1  (m-half)
    const int wn   = wave & 3;       // 0..3  (n-quarter)
    const int ln16 = lane & 15;
    const int q    = (lane >> 4) & 3;

    // bijective XCD chunk swizzle (512 blocks, 512 % 8 == 0)
    const int id  = blockIdx.x;
    const int swz = (id & 7) * 64 + (id >> 3);
    const int M0  = (swz & 15) * 256;        // batch tile
    const int h0  = ((swz >> 4) & 7) * 64;   // hidden tile (64 units)
    const int d   = swz >> 7;                // depth
    const int s   = d * HU_;

    const short* A1p = Apk + (size_t)d * a_dstride;
    const short* A2p = Hpk + (size_t)(j * 4 + d) * (4096 * PK_SUB);
    const short* W1  = Wihb + (size_t)(d * 2 + j) * NG * ISZ;
    const short* W2  = Whhb + (size_t)(d * 2 + j) * NG * HU_;
    const float* bi_ = b_ih + (size_t)(d * 2 + j) * NG;
    const float* bh_ = b_hh + (size_t)(d * 2 + j) * NG;

    // B staging geometry (512thr x 16B = 64 rows x 128B per issue, pre-swizzled source)
    const int srow = tid >> 3;
    const int scol = (((tid & 7) ^ ((tid >> 3) & 7)) << 3);

    unsigned b1off[4], b2off[4];
#pragma unroll
    for (int it = 0; it < 4; ++it) {
        const int gr = GROW(it * 64 + srow);
        b1off[it] = (unsigned)(gr * ISZ + scol);
        b2off[it] = (unsigned)(gr * HU_ + scol);
    }

    const int swz0 = ((q    ) ^ (ln16 & 7)) << 4;
    const int swz1 = ((q + 4) ^ (ln16 & 7)) << 4;
    const char* ldsb = (const char*)lds;

    const int row16 = (M0 >> 4) + wm * 8;    // packed row-block base for this wave
    const int l8    = lane * 8;

    f32x4 acc[8][4];
#pragma unroll
    for (int i = 0; i < 8; ++i)
#pragma unroll
        for (int n = 0; n < 4; ++n) acc[i][n] = (f32x4){0.f, 0.f, 0.f, 0.f};

    bf16x8 aLo[4][2], aHi[4][2];
    bf16x8 b01[2][2], b23[2][2];

    auto stB = [&](const short* bsrc, const unsigned* bo, int nbuf, int kofs) {
#pragma unroll
        for (int it = 0; it < 4; ++it)
            async16(bsrc + bo[it] + kofs, lds + nbuf * 16384 + (it * 64 + wave * 8) * 64);
    };
    auto ldA = [&](const short* apk, int nkb, int kblk) {
#pragma unroll
        for (int mtl = 0; mtl < 4; ++mtl) {
            const short* p = apk + ((size_t)(row16 + mtl) * nkb + kblk) * PK_SUB + l8;
            aLo[mtl][0] = *(const bf16x8*)(p);
            aLo[mtl][1] = *(const bf16x8*)(p + PK_SUB);
        }
#pragma unroll
        for (int mtl = 0; mtl < 4; ++mtl) {
            const short* p = apk + ((size_t)(row16 + 4 + mtl) * nkb + kblk) * PK_SUB + l8;
            aHi[mtl][0] = *(const bf16x8*)(p);
            aHi[mtl][1] = *(const bf16x8*)(p + PK_SUB);
        }
    };
    auto rdB = [&](bf16x8 (&bb)[2][2], int buf, int nt0) {
#pragma unroll
        for (int nn = 0; nn < 2; ++nn) {
            const int row = wn * 64 + (nt0 + nn) * 16 + ln16;
            bb[nn][0] = *(const bf16x8*)(ldsb + buf * 32768 + row * 128 + swz0);
            bb[nn][1] = *(const bf16x8*)(ldsb + buf * 32768 + row * 128 + swz1);
        }
    };

    auto do_tile = [&](const short* apk, int nkb, int kblk, int buf,
                       const short* bsrc, const unsigned* bo, int bkofs, bool doStage) {
        ldA(apk, nkb, kblk);                      // A(t): 16 coalesced global loads
        asm volatile("" ::: "memory");            // pin order: A issues before B staging
        if (doStage) stB(bsrc, bo, buf ^ 1, bkofs);
        rdB(b01, buf, 0);
        MMA_BLK(b01, aLo, 0, 0);
        rdB(b23, buf, 2);
        MMA_BLK(b23, aLo, 0, 2);
        MMA_BLK(b23, aHi, 4, 2);
        MMA_BLK(b01, aHi, 4, 0);
        VM_BAR(0);                                // B(t+1) landed; A(t) already consumed
    };

    // prologue: stage B(0) into buf 0, drain
    stB(W1, b1off, 0, 0);
    VM_BAR(0);

    // K1: tiles 0..14 (stage next K1 B), t=15 (stage first K2 B)
    for (int t = 0; t < 15; ++t)
        do_tile(A1p, PK_NKB1, t * 2, t & 1, W1, b1off, (t + 1) * 64, true);
    do_tile(A1p, PK_NKB1, 30, 1, W2, b2off, 0, true);
    // K2: tiles 16..22 (stage next K2 B), t=23 (no stage)
    for (int t = 16; t < 23; ++t)
        do_tile(A2p, PK_NKB2, (t - 16) * 2, t & 1, W2, b2off, (t - 15) * 64, true);
    do_tile(A2p, PK_NKB2, 14, 1, W2, b2off, 0, false);

    // epilogue: fused LSTM cell. D layout: col = lane&15, row = q*4 + reg.
    const int h   = h0 + wn * 16 + ln16;       // 0..511
    const int col = s + h;                     // 0..2047
    const float b_i = bi_[h]          + bh_[h];
    const float b_f = bi_[512 + h]    + bh_[512 + h];
    const float b_g = bi_[1024 + h]   + bh_[1024 + h];
    const float b_o = bi_[1536 + h]   + bh_[1536 + h];
#pragma unroll
    for (int mt = 0; mt < 8; ++mt) {
#pragma unroll
        for (int r = 0; r < 4; ++r) {
            const int m = M0 + wm * 128 + mt * 16 + q * 4 + r;
            const float hx = state[((size_t)(j)     * B_ + m) * SW + col];  // state[0,j]
            const float cx = state[((size_t)(2 + j) * B_ + m) * SW + col];  // state[1,j]
            const float gi = sigm(acc[mt][0][r] + b_i);
            const float gf = sigm(acc[mt][1][r] + b_f);
            const float gg = tanh_f(acc[mt][2][r] + b_g);
            const float go = sigm(acc[mt][3][r] + b_o);
            const float c_out = gf * cx + gi * gg;
            const float h_out = go * tanh_f(c_out);
            out_state[((size_t)(j)     * B_ + m) * OHW + col] = h_out + hx;  // newH[j]
            out_state[((size_t)(2 + j) * B_ + m) * OHW + col] = c_out;       // newC[j]
            if (j == 1) out_ho[(size_t)m * OHW + col] = h_out + hx;
            else        h0b[((size_t)d * B_ + m) * HU_ + h] = f2bf(h_out);   // pre-residual
        }
    }
}

// ---------------------------------------------------------------- proj3: dec1 = input + h0 @ proj_W^T + proj_b
// (unchanged R8 structure; epilogue now writes PACKED dec1 for gates3's A-direct path)
__global__ __launch_bounds__(256, 2) void proj3_kernel(
    const short* __restrict__ h0b, const short* __restrict__ PWb,
    const float* __restrict__ input, const float* __restrict__ proj_b,
    short* __restrict__ dec1pk)
{
    extern __shared__ short lds[];   // 2 bufs x (A 128x64 + B 128x64) bf16 = 65536 B

    const int t    = threadIdx.x;
    const int wave = t >> 6, lane = t & 63;
    const int ln16 = lane & 15, q = lane >> 4;

    const int id  = blockIdx.x;
    const int swz = (id & 7) * 128 + (id >> 3);
    const int M0  = (swz & 31) * 128;
    const int N0  = ((swz >> 5) & 7) * 128;
    const int d   = swz >> 8;

    const short* A = h0b + (size_t)d * B_ * HU_;
    const short* Bm = PWb;

    const int srow = t >> 3;
    const int scol = (((t & 7) ^ ((t >> 3) & 7)) << 3);

    unsigned aoff[4], boff[4];
#pragma unroll
    for (int it = 0; it < 4; ++it) {
        aoff[it] = (unsigned)((M0 + it * 32 + srow) * HU_ + scol);
        boff[it] = (unsigned)((N0 + it * 32 + srow) * HU_ + scol);
    }

    f32x4 acc[2][8];
#pragma unroll
    for (int mt = 0; mt < 2; mt++)
#pragma unroll
        for (int nt = 0; nt < 8; nt++) acc[mt][nt] = (f32x4){0.f, 0.f, 0.f, 0.f};

    auto stage = [&](int nbuf, int k0) {
#pragma unroll
        for (int it = 0; it < 4; it++)
            async16(A + aoff[it] + k0, lds + nbuf * 16384 + (it * 32 + wave * 8) * 64);
#pragma unroll
        for (int it = 0; it < 4; it++)
            async16(Bm + boff[it] + k0, lds + nbuf * 16384 + 8192 + (it * 32 + wave * 8) * 64);
    };
    auto compute = [&](int buf) {
        const short* sA = lds + buf * 16384;
        const short* sB = lds + buf * 16384 + 8192;
#pragma unroll
        for (int ks = 0; ks < 2; ks++) {
            const int kb = ks * 4 + q;
            bf16x8 a[2], b[8];
#pragma unroll
            for (int mt = 0; mt < 2; mt++) {
                const int m = wave * 32 + mt * 16 + ln16;
                a[mt] = *(const bf16x8*)&sA[m * 64 + ((kb ^ (m & 7)) << 3)];
            }
#pragma unroll
            for (int nt = 0; nt < 8; nt++) {
                const int n = nt * 16 + ln16;
                b[nt] = *(const bf16x8*)&sB[n * 64 + ((kb ^ (n & 7)) << 3)];
            }
#pragma unroll
            for (int mt = 0; mt < 2; mt++)
#pragma unroll
                for (int nt = 0; nt < 8; nt++)
                    acc[mt][nt] = __builtin_amdgcn_mfma_f32_16x16x32_bf16(a[mt], b[nt], acc[mt][nt], 0, 0, 0);
        }
    };

    stage(0, 0);
    VM_BAR(0);
    for (int tt = 0; tt < 7; ++tt) {
        const int buf = tt & 1;
        stage(buf ^ 1, (tt + 1) * 64);
        compute(buf);
        VM_BAR(0);
    }
    compute(1);

    // epilogue: y = acc + input + proj_b -> PACKED bf16 dec1
    const size_t dbase = (size_t)d * PK_DSTR;
#pragma unroll
    for (int mt = 0; mt < 2; mt++) {
#pragma unroll
        for (int nt = 0; nt < 8; nt++) {
            const int n = N0 + nt * 16 + ln16;
            const float pb = proj_b[n];
            const size_t nPart = ((size_t)(n >> 5)) * PK_SUB + (((n >> 3) & 3) * 16) * 8 + (n & 7);
#pragma unroll
            for (int r = 0; r < 4; r++) {
                const int m = M0 + wave * 32 + mt * 16 + q * 4 + r;
                const float y = acc[mt][nt][r] + input[(size_t)m * ISZ + n] + pb;
                dec1pk[dbase + ((size_t)(m >> 4) * PK_NKB1) * PK_SUB + nPart + (m & 15) * 8] = f2bf(y);
            }
        }
    }
}

// ---------------------------------------------------------------- launch
extern "C" void kernel_launch(void* const* d_in, const int* in_sizes, int n_in,
                              void* d_out, int out_size, void* d_ws, size_t ws_size,
                              hipStream_t stream)
{
    const float* input  = (const float*)d_in[0];
    const float* state  = (const float*)d_in[1];
    const float* W_ih   = (const float*)d_in[2];
    const float* W_hh   = (const float*)d_in[3];
    const float* b_ih   = (const float*)d_in[4];
    const float* b_hh   = (const float*)d_in[5];
    const float* proj_W = (const float*)d_in[6];
    const float* proj_b = (const float*)d_in[7];

    float* out_ho    = (float*)d_out;                    // (B, OHW)
    float* out_state = out_ho + (size_t)B_ * OHW;        // (2, 2, B, OHW)

    short* ws     = (short*)d_ws;
    short* Wihb   = ws;                                  // 8 x NG x ISZ   (32 MB)
    short* Whhb   = Wihb + (size_t)8 * NG * ISZ;         // 8 x NG x HU    (16 MB)
    short* PWb    = Whhb + (size_t)8 * NG * HU_;         // ISZ x HU       ( 1 MB)
    short* Hpk    = PWb  + (size_t)ISZ * HU_;            // packed h-state (32 MB)
    short* h0b    = Hpk  + (size_t)2 * B_ * OHW;         // 4 x B x HU     (16 MB)
    short* dec1pk = h0b  + (size_t)4 * B_ * HU_;         // packed dec1    (32 MB)
    short* Xpk    = dec1pk;                              // packed input — aliases dec1pk head
                                                         // (Xpk dead before proj3 writes dec1pk)

    static bool s_attr = false;
    if (!s_attr) {
        (void)hipFuncSetAttribute(reinterpret_cast<const void*>(gates3_kernel),
                                  hipFuncAttributeMaxDynamicSharedMemorySize, 65536);
        (void)hipFuncSetAttribute(reinterpret_cast<const void*>(proj3_kernel),
                                  hipFuncAttributeMaxDynamicSharedMemorySize, 65536);
        s_attr = true;
    }

    {
        long n;
        n = (long)8 * NG * ISZ;  cvt_kernel<<<dim3((unsigned)(n / 8 / 256)), 256, 0, stream>>>(W_ih,   Wihb, n);
        n = (long)8 * NG * HU_;  cvt_kernel<<<dim3((unsigned)(n / 8 / 256)), 256, 0, stream>>>(W_hh,   Whhb, n);
        n = (long)ISZ * HU_;     cvt_kernel<<<dim3((unsigned)(n / 8 / 256)), 256, 0, stream>>>(proj_W, PWb,  n);
        n = (long)B_ * ISZ;      cvt_pack_kernel<<<dim3((unsigned)(n / 8 / 256)), 256, 0, stream>>>(input, Xpk);
        n = (long)2 * B_ * OHW;  cvt_h_pack_kernel<<<dim3((unsigned)(n / 8 / 256)), 256, 0, stream>>>(state, Hpk);
    }

    // stack 0 (all 4 depths): gates + cell, writes newH[0]/newC[0] and h0b
    gates3_kernel<<<dim3(512), dim3(512), 65536, stream>>>(Xpk, 0L, Hpk, Wihb, Whhb,
                                                           b_ih, b_hh, state,
                                                           out_ho, out_state, h0b, 0);
    // dec1 = input + h_out0 @ proj_W^T + proj_b (per depth), packed bf16
    proj3_kernel<<<dim3(1024), dim3(256), 65536, stream>>>(h0b, PWb, input, proj_b, dec1pk);
    // stack 1 (all 4 depths): gates + cell, writes newH[1]/newC[1] and ho
    gates3_kernel<<<dim3(512), dim3(512), 65536, stream>>>(dec1pk, (long)PK_DSTR, Hpk, Wihb, Whhb,
                                                           b_ih, b_hh, state,
                                                           out_ho, out_state, nullptr, 1);
}